// Round 5
// baseline (28.692 us; speedup 1.0000x reference)
//
#include <hip/hip_runtime.h>
#include <math.h>

#define NTH 256

__device__ __forceinline__ float frcp(float x) { return __builtin_amdgcn_rcpf(x); }

__device__ __forceinline__ float get_comp(const float4& v, int c) {
    switch (c) { case 0: return v.x; case 1: return v.y; case 2: return v.z; default: return v.w; }
}

// Clip directed segment A->B against rotated rect (center (ocx,ocy), axis (c,s),
// half-extents heu,hev); return cross(A',B') of clipped sub-segment (0 if empty).
__device__ __forceinline__ float clip_cross(
    float ax, float ay, float bx, float by,
    float ocx, float ocy, float c, float s,
    float heu, float hev)
{
    float dx = bx - ax, dy = by - ay;
    float rx = ax - ocx, ry = ay - ocy;
    float s0u = rx*c + ry*s,  sdu = dx*c + dy*s;
    float s0v = ry*c - rx*s,  sdv = dy*c - dx*s;
    float iu = frcp(sdu), iv = frcp(sdv);
    float ta = (-heu - s0u)*iu, tb = (heu - s0u)*iu;
    float tc = (-hev - s0v)*iv, td = (hev - s0v)*iv;
    float tlu = fminf(ta, tb), thu = fmaxf(ta, tb);
    float tlv = fminf(tc, td), thv = fmaxf(tc, td);
    float tin  = fmaxf(fmaxf(tlu, tlv), 0.0f);
    float tout = fminf(fminf(thu, thv), 1.0f);
    bool ok = tin < tout;
    float Ax = ax + tin*dx,  Ay = ay + tin*dy;
    float Bx = ax + tout*dx, By = ay + tout*dy;
    float cr = Ax*By - Ay*Bx;
    return ok ? cr : 0.0f;
}

__device__ __forceinline__ float iou_loss_one(const float b1[7], const float b2[7], float w)
{
    float zmax = fminf(b1[2]+0.5f*b1[5], b2[2]+0.5f*b2[5]);
    float zmin = fmaxf(b1[2]-0.5f*b1[5], b2[2]-0.5f*b2[5]);
    float dz = fmaxf(zmax - zmin, 0.0f);
    float v1 = b1[3]*b1[4]*b1[5];
    float v2 = b2[3]*b2[4]*b2[5];

    float ox = b2[0] - b1[0], oy = b2[1] - b1[1];
    float ca1 = __cosf(b1[6]), sa1 = __sinf(b1[6]);
    float ca2 = __cosf(b2[6]), sa2 = __sinf(b2[6]);
    float hw1 = 0.5f*b1[3], hl1 = 0.5f*b1[4];
    float hw2 = 0.5f*b2[3], hl2 = 0.5f*b2[4];

    const float dxs[4] = {0.5f,-0.5f,-0.5f,0.5f};
    const float dys[4] = {0.5f,0.5f,-0.5f,-0.5f};
    float px[4], py[4], qx[4], qy[4];
    #pragma unroll
    for (int k = 0; k < 4; ++k) {
        float xs = dxs[k]*b1[3], ys = dys[k]*b1[4];
        px[k] = xs*ca1 - ys*sa1;
        py[k] = xs*sa1 + ys*ca1;
        float xs2 = dxs[k]*b2[3], ys2 = dys[k]*b2[4];
        qx[k] = ox + xs2*ca2 - ys2*sa2;
        qy[k] = oy + xs2*sa2 + ys2*ca2;
    }

    float s2 = 0.0f;
    #pragma unroll
    for (int k = 0; k < 4; ++k) {
        int kn = (k+1)&3;
        s2 += clip_cross(px[k],py[k], px[kn],py[kn], ox,oy, ca2,sa2, hw2,hl2);
        s2 += clip_cross(qx[k],qy[k], qx[kn],qy[kn], 0.0f,0.0f, ca1,sa1, hw1,hl1);
    }
    float area = 0.5f*fabsf(s2);

    float inter_vol = area * dz;
    float iou = inter_vol * frcp(v1 + v2 - inter_vol + 1e-8f);
    return (1.0f - iou) * w;
}

__global__ __launch_bounds__(NTH) void iou_loss_kernel(
    const float* __restrict__ pred, const float* __restrict__ target,
    const float* __restrict__ weight, float* __restrict__ partial,
    unsigned* __restrict__ counter, float* __restrict__ out,
    int n, int nblocks, double inv_n)
{
    int t = blockIdx.x * blockDim.x + threadIdx.x;
    int i4 = t * 4;
    float loss = 0.0f;
    if (i4 + 3 < n) {
        // 4 rows = 28 floats = 7 x float4, base 112B-aligned.
        float4 p[7], q[7];
        const float4* pp = reinterpret_cast<const float4*>(pred + i4*7);
        const float4* qq = reinterpret_cast<const float4*>(target + i4*7);
        #pragma unroll
        for (int k = 0; k < 7; ++k) { p[k] = pp[k]; q[k] = qq[k]; }
        float4 wv = *reinterpret_cast<const float4*>(weight + i4);

        #pragma unroll
        for (int r = 0; r < 4; ++r) {
            float b1[7], b2[7];
            #pragma unroll
            for (int j = 0; j < 7; ++j) {
                int f = r*7 + j;
                b1[j] = get_comp(p[f >> 2], f & 3);
                b2[j] = get_comp(q[f >> 2], f & 3);
            }
            float w = get_comp(wv, r);
            loss += iou_loss_one(b1, b2, w);
        }
    } else {
        for (int r = 0; r < 4; ++r) {
            int i = i4 + r;
            if (i < n) {
                float b1[7], b2[7];
                #pragma unroll
                for (int j = 0; j < 7; ++j) { b1[j] = pred[i*7+j]; b2[j] = target[i*7+j]; }
                loss += iou_loss_one(b1, b2, weight[i]);
            }
        }
    }

    // ---- block reduction ----
    #pragma unroll
    for (int off = 32; off > 0; off >>= 1) loss += __shfl_down(loss, off, 64);
    __shared__ float wsum[NTH/64];
    __shared__ bool is_last;
    int lane = threadIdx.x & 63, wid = threadIdx.x >> 6;
    if (lane == 0) wsum[wid] = loss;
    __syncthreads();
    if (threadIdx.x == 0) {
        float s = 0.0f;
        #pragma unroll
        for (int w = 0; w < NTH/64; ++w) s += wsum[w];
        partial[blockIdx.x] = s;
        __threadfence();                       // publish partial (device scope)
        unsigned prev = atomicAdd(counter, 1u);
        is_last = (prev == (unsigned)(nblocks - 1));
    }
    __syncthreads();

    // ---- last block: final reduction in double ----
    if (is_last) {
        __threadfence();                       // acquire all partials
        double s = 0.0;
        for (int j = threadIdx.x; j < nblocks; j += NTH) s += (double)partial[j];
        #pragma unroll
        for (int off = 32; off > 0; off >>= 1) s += __shfl_down(s, off, 64);
        __shared__ double dsum[NTH/64];
        if (lane == 0) dsum[wid] = s;
        __syncthreads();
        if (threadIdx.x == 0) {
            double tot = 0.0;
            #pragma unroll
            for (int w = 0; w < NTH/64; ++w) tot += dsum[w];
            out[0] = (float)(tot * inv_n);
        }
    }
}

extern "C" void kernel_launch(void* const* d_in, const int* in_sizes, int n_in,
                              void* d_out, int out_size, void* d_ws, size_t ws_size,
                              hipStream_t stream) {
    const float* pred   = (const float*)d_in[0];
    const float* target = (const float*)d_in[1];
    const float* weight = (const float*)d_in[2];
    int n = in_sizes[2];
    unsigned* counter = (unsigned*)d_ws;
    float* partial = (float*)((char*)d_ws + 256);
    hipMemsetAsync(d_ws, 0, 4, stream);        // counter = 0 each call
    int nt = (n + 3) / 4;
    int nblocks = (nt + NTH - 1) / NTH;
    hipLaunchKernelGGL(iou_loss_kernel, dim3(nblocks), dim3(NTH), 0, stream,
                       pred, target, weight, partial, counter, (float*)d_out,
                       n, nblocks, 1.0 / (double)n);
}

// Round 6
// 15.681 us; speedup vs baseline: 1.8298x; 1.8298x over previous
//
#include <hip/hip_runtime.h>
#include <math.h>

#define NTH 256

__device__ __forceinline__ float frcp(float x) { return __builtin_amdgcn_rcpf(x); }

// Clip directed segment A->B against rotated rect (center (ocx,ocy), axis (c,s),
// half-extents heu,hev); return cross(A',B') of clipped sub-segment (0 if empty).
__device__ __forceinline__ float clip_cross(
    float ax, float ay, float bx, float by,
    float ocx, float ocy, float c, float s,
    float heu, float hev)
{
    float dx = bx - ax, dy = by - ay;
    float rx = ax - ocx, ry = ay - ocy;
    float s0u = rx*c + ry*s,  sdu = dx*c + dy*s;
    float s0v = ry*c - rx*s,  sdv = dy*c - dx*s;
    float iu = frcp(sdu), iv = frcp(sdv);
    float ta = (-heu - s0u)*iu, tb = (heu - s0u)*iu;
    float tc = (-hev - s0v)*iv, td = (hev - s0v)*iv;
    float tlu = fminf(ta, tb), thu = fmaxf(ta, tb);
    float tlv = fminf(tc, td), thv = fmaxf(tc, td);
    float tin  = fmaxf(fmaxf(tlu, tlv), 0.0f);
    float tout = fminf(fminf(thu, thv), 1.0f);
    bool ok = tin < tout;
    float Ax = ax + tin*dx,  Ay = ay + tin*dy;
    float Bx = ax + tout*dx, By = ay + tout*dy;
    float cr = Ax*By - Ay*Bx;
    return ok ? cr : 0.0f;
}

__device__ __forceinline__ float iou_loss_one(const float b1[7], const float b2[7], float w)
{
    float zmax = fminf(b1[2]+0.5f*b1[5], b2[2]+0.5f*b2[5]);
    float zmin = fmaxf(b1[2]-0.5f*b1[5], b2[2]-0.5f*b2[5]);
    float dz = fmaxf(zmax - zmin, 0.0f);
    float v1 = b1[3]*b1[4]*b1[5];
    float v2 = b2[3]*b2[4]*b2[5];

    float ox = b2[0] - b1[0], oy = b2[1] - b1[1];
    float ca1 = __cosf(b1[6]), sa1 = __sinf(b1[6]);
    float ca2 = __cosf(b2[6]), sa2 = __sinf(b2[6]);
    float hw1 = 0.5f*b1[3], hl1 = 0.5f*b1[4];
    float hw2 = 0.5f*b2[3], hl2 = 0.5f*b2[4];

    const float dxs[4] = {0.5f,-0.5f,-0.5f,0.5f};
    const float dys[4] = {0.5f,0.5f,-0.5f,-0.5f};
    float px[4], py[4], qx[4], qy[4];
    #pragma unroll
    for (int k = 0; k < 4; ++k) {
        float xs = dxs[k]*b1[3], ys = dys[k]*b1[4];
        px[k] = xs*ca1 - ys*sa1;
        py[k] = xs*sa1 + ys*ca1;
        float xs2 = dxs[k]*b2[3], ys2 = dys[k]*b2[4];
        qx[k] = ox + xs2*ca2 - ys2*sa2;
        qy[k] = oy + xs2*sa2 + ys2*ca2;
    }

    float s2 = 0.0f;
    #pragma unroll
    for (int k = 0; k < 4; ++k) {
        int kn = (k+1)&3;
        s2 += clip_cross(px[k],py[k], px[kn],py[kn], ox,oy, ca2,sa2, hw2,hl2);
        s2 += clip_cross(qx[k],qy[k], qx[kn],qy[kn], 0.0f,0.0f, ca1,sa1, hw1,hl1);
    }
    float area = 0.5f*fabsf(s2);

    float inter_vol = area * dz;
    float iou = inter_vol * frcp(v1 + v2 - inter_vol + 1e-8f);
    return (1.0f - iou) * w;
}

__global__ __launch_bounds__(NTH) void iou_loss_kernel(
    const float* __restrict__ pred, const float* __restrict__ target,
    const float* __restrict__ weight, float* __restrict__ partial, int n)
{
    int i = blockIdx.x * blockDim.x + threadIdx.x;
    float loss = 0.0f;
    if (i < n) {
        // 1 row/thread: 7 scalar dwords per array. A wave's loads cover 64
        // contiguous rows (1792B = 28 cache lines) reused across all 7 loads
        // via L1 — fully coalesced in aggregate, no over-fetch.
        float b1[7], b2[7];
        #pragma unroll
        for (int j = 0; j < 7; ++j) { b1[j] = pred[i*7+j]; b2[j] = target[i*7+j]; }
        loss = iou_loss_one(b1, b2, weight[i]);
    }

    // block reduction -> per-block partial (no atomics, no fences)
    #pragma unroll
    for (int off = 32; off > 0; off >>= 1) loss += __shfl_down(loss, off, 64);
    __shared__ float wsum[NTH/64];
    int lane = threadIdx.x & 63, wid = threadIdx.x >> 6;
    if (lane == 0) wsum[wid] = loss;
    __syncthreads();
    if (threadIdx.x == 0) {
        float s = 0.0f;
        #pragma unroll
        for (int w = 0; w < NTH/64; ++w) s += wsum[w];
        partial[blockIdx.x] = s;
    }
}

__global__ __launch_bounds__(NTH) void reduce_kernel(
    const float* __restrict__ partial, int nb, float* __restrict__ out, double inv_n)
{
    double s = 0.0;
    for (int j = threadIdx.x; j < nb; j += NTH) s += (double)partial[j];
    #pragma unroll
    for (int off = 32; off > 0; off >>= 1) s += __shfl_down(s, off, 64);
    __shared__ double wsum[NTH/64];
    int lane = threadIdx.x & 63, wid = threadIdx.x >> 6;
    if (lane == 0) wsum[wid] = s;
    __syncthreads();
    if (threadIdx.x == 0) {
        double tot = 0.0;
        #pragma unroll
        for (int w = 0; w < NTH/64; ++w) tot += wsum[w];
        out[0] = (float)(tot * inv_n);
    }
}

extern "C" void kernel_launch(void* const* d_in, const int* in_sizes, int n_in,
                              void* d_out, int out_size, void* d_ws, size_t ws_size,
                              hipStream_t stream) {
    const float* pred   = (const float*)d_in[0];
    const float* target = (const float*)d_in[1];
    const float* weight = (const float*)d_in[2];
    int n = in_sizes[2];
    float* partial = (float*)d_ws;
    int nblocks = (n + NTH - 1) / NTH;
    hipLaunchKernelGGL(iou_loss_kernel, dim3(nblocks), dim3(NTH), 0, stream,
                       pred, target, weight, partial, n);
    hipLaunchKernelGGL(reduce_kernel, dim3(1), dim3(NTH), 0, stream,
                       partial, nblocks, (float*)d_out, 1.0 / (double)n);
}